// Round 7
// baseline (473.750 us; speedup 1.0000x reference)
//
#include <hip/hip_runtime.h>

#define BATCH 262144
#define MARGIN 1e-5f
#define LIST_CAP (1u<<20)

typedef __attribute__((ext_vector_type(8))) short short8;
typedef __attribute__((ext_vector_type(16))) float f32x16;

// ---------------- workspace layout (bytes) ----------------
// 0       : Rt64 f64[128][128]  Rt64[j*128+k] = R[k][j]      (131072)
// 131072  : img  u16: i1h[16384] i1l[16384] i2h[16384] i2l[16384] (131072)
//           img1 frag(kb,jc): lane l,e -> R[kb*32+(l&31)][jc*16+8*(l>>5)+e]  (mm1 B)
//           img2 frag(jb,kc): lane l,e -> R[kc*16+8*(l>>5)+e][jb*32+(l&31)]  (mm2 B)
// 262144  : counter u32
// 262912  : list u32[LIST_CAP]  (row ids, dups ok)

__device__ __forceinline__ unsigned f2bf(float f) {
  unsigned u = __float_as_uint(f);
  return (u + 0x7FFFu + ((u >> 16) & 1u)) >> 16;   // RTN-even bf16
}
__device__ __forceinline__ unsigned packsplit(float f) {
  unsigned h = f2bf(f);
  float hf = __uint_as_float(h << 16);
  unsigned l = f2bf(f - hf);
  return (h << 16) | l;
}

// =======================================================================
// K_pre: register-resident Gauss-Jordan inversion of M = I + A (no
// pivoting; cond ~1.5). launch_bounds(1024,4): 4 waves/EU == exactly one
// 1024-thr block resident -> 128-VGPR budget, so M[16] f64 stays in
// registers (prior rounds: 64-VGPR budget heuristic -> full scratch
// spill, 27 MB FETCH, 150-320 us). One barrier per iteration.
// R = 2*(I+A)^-1 - I.
// =======================================================================
__global__ __launch_bounds__(1024, 4)
void kpre(const float* __restrict__ skew, double* __restrict__ Rt64,
          unsigned short* __restrict__ img)
{
  __shared__ double colk[2][128];   // raw pivot-column values per row
  __shared__ double praw[2][128];   // raw (unscaled) pivot row
  const int tid = threadIdx.x;
  const int i = tid >> 3;
  const int s = tid & 7;

  double M[16];
  #pragma unroll
  for (int e = 0; e < 16; ++e) {
    int j = s + 8*e;
    double v;
    if (i == j)      v = 1.0;
    else if (i < j)  v =  (double)skew[i*127 - (i*(i-1))/2 + (j - i - 1)];
    else             v = -(double)skew[j*127 - (j*(j-1))/2 + (i - j - 1)];
    M[e] = v;
  }
  // prologue: publish column 0 and raw row 0
  if (s == 0) colk[0][i] = M[0];
  if (i == 0) {
    #pragma unroll
    for (int e = 0; e < 16; ++e) praw[0][s + 8*e] = M[e];
  }
  __syncthreads();

  for (int k = 0; k < 128; ++k) {
    const int p = k & 1, np = p ^ 1;
    const int kp1 = k + 1;
    const int ns = kp1 & 7, ne = kp1 >> 3;   // k=127 -> ne=16: no publish
    const double rec = 1.0 / colk[p][k];     // redundant in all threads
    if (i == k) {
      #pragma unroll
      for (int e = 0; e < 16; ++e) {
        int j = s + 8*e;
        double v = (j == k) ? rec : M[e] * rec;
        M[e] = v;
        if (s == ns && e == ne) colk[np][i] = v;
      }
    } else {
      const double t = colk[p][i] * rec;
      #pragma unroll
      for (int e = 0; e < 16; ++e) {
        int j = s + 8*e;
        double v = (j == k) ? (0.0 - t) : fma(-t, praw[p][j], M[e]);
        M[e] = v;
        if (i == kp1) praw[np][j] = v;           // next raw pivot row
        if (s == ns && e == ne) colk[np][i] = v; // next raw pivot column
      }
    }
    __syncthreads();
  }

  #pragma unroll
  for (int e = 0; e < 16; ++e) {
    int j = s + 8*e;
    double v = 2.0 * M[e] - ((i == j) ? 1.0 : 0.0);    // R[i][j]
    Rt64[j*128 + i] = v;
    float r32 = (float)v;
    unsigned h = f2bf(r32);
    unsigned l = f2bf(r32 - __uint_as_float(h << 16));
    int off1 = (((i>>5)*8 + (j>>4))*64 + ((((j>>3)&1)<<5) | (i&31)))*8 + (j&7);
    img[off1]          = (unsigned short)h;
    img[16384 + off1]  = (unsigned short)l;
    int off2 = (((j>>5)*8 + (i>>4))*64 + ((((i>>3)&1)<<5) | (j&31)))*8 + (i&7);
    img[32768 + off2]  = (unsigned short)h;
    img[49152 + off2]  = (unsigned short)l;
  }
}

// =======================================================================
// K_main: fused rotate+quantize+reconstruct. 1024 blocks x 256 thr.
// B-fragments in registers for the whole kernel. X/Q LDS double-buffered.
// Barriers are lgkm-only (no vmcnt drain): out-stores and next-chunk
// prefetch loads stay in flight across barriers.
// =======================================================================
#define MM3(ACC, XH, XL, BH, BL)                                        \
  ACC = __builtin_amdgcn_mfma_f32_32x32x16_bf16(XH, BH, ACC, 0, 0, 0);  \
  ACC = __builtin_amdgcn_mfma_f32_32x32x16_bf16(XL, BH, ACC, 0, 0, 0);  \
  ACC = __builtin_amdgcn_mfma_f32_32x32x16_bf16(XH, BL, ACC, 0, 0, 0);

#define LGKM_BAR()                                                      \
  asm volatile("s_waitcnt lgkmcnt(0)" ::: "memory");                    \
  __builtin_amdgcn_s_barrier();                                         \
  __builtin_amdgcn_sched_barrier(0);

__global__ __launch_bounds__(256, 2)
void kmain(const float* __restrict__ x, const float* __restrict__ mean,
           const float* __restrict__ cent, const unsigned short* __restrict__ img,
           float* __restrict__ out,
           unsigned int* __restrict__ counter, unsigned int* __restrict__ list)
{
  __shared__ __align__(16) unsigned short Xh[2][32*128];   // 2 x 8 KB (swizzled)
  __shared__ __align__(16) unsigned short Xl[2][32*128];
  __shared__ __align__(16) unsigned short Qh[2][32*128];
  __shared__ __align__(16) unsigned short Ql[2][32*128];
  __shared__ float norms[2][32];
  __shared__ float invs[2][32];

  const int tid = threadIdx.x, lane = tid & 63, w = tid >> 6;
  const int al = lane & 31, ah = lane >> 5;

  // ---- loop-invariant B fragments -> registers (128 VGPRs) ----
  short8 B1h[8], B1l[8], B2h[8], B2l[8];
  #pragma unroll
  for (int t = 0; t < 8; ++t) {
    size_t o = (size_t)((w*8 + t)*64 + lane)*8;
    B1h[t] = *(const short8*)(img +         o);
    B1l[t] = *(const short8*)(img + 16384 + o);
    B2h[t] = *(const short8*)(img + 32768 + o);
    B2l[t] = *(const short8*)(img + 49152 + o);
  }

  const float c0 = cent[0], c1 = cent[1], c2 = cent[2], c3 = cent[3];
  const float c4 = cent[4], c5 = cent[5], c6 = cent[6], c7 = cent[7];
  const float mid0 = 0.5f*(c0+c1), mid1 = 0.5f*(c1+c2), mid2 = 0.5f*(c2+c3),
              mid3 = 0.5f*(c3+c4), mid4 = 0.5f*(c4+c5), mid5 = 0.5f*(c5+c6),
              mid6 = 0.5f*(c6+c7);
  const unsigned qt0 = packsplit(c0), qt1 = packsplit(c1), qt2 = packsplit(c2),
                 qt3 = packsplit(c3), qt4 = packsplit(c4), qt5 = packsplit(c5),
                 qt6 = packsplit(c6), qt7 = packsplit(c7);

  const float2 mean2 = *(const float2*)(mean + 2*lane);
  const float meanv = mean[w*32 + al];

  const int row0 = blockIdx.x * 256;

  // prefetch chunk 0
  float2 xpf[8];
  #pragma unroll
  for (int rr = 0; rr < 8; ++rr)
    xpf[rr] = *(const float2*)(x + (size_t)(row0 + w*8 + rr)*128 + 2*lane);

  for (int ch = 0; ch < 8; ++ch) {
    const int chb = row0 + ch*32;
    const int p = ch & 1;

    // ---- Phase A: issue next-chunk loads; pack current -> X[p] ----
    float2 xn[8];
    if (ch < 7) {
      #pragma unroll
      for (int rr = 0; rr < 8; ++rr)
        xn[rr] = *(const float2*)(x + (size_t)(chb + 32 + w*8 + rr)*128 + 2*lane);
    }
    #pragma unroll
    for (int rr = 0; rr < 8; ++rr) {
      const int r = w*8 + rr;
      float a = xpf[rr].x - mean2.x;
      float b = xpf[rr].y - mean2.y;
      float sq = fmaf(a, a, b*b);
      sq += __shfl_xor(sq, 1);  sq += __shfl_xor(sq, 2);  sq += __shfl_xor(sq, 4);
      sq += __shfl_xor(sq, 8);  sq += __shfl_xor(sq, 16); sq += __shfl_xor(sq, 32);
      unsigned pa = packsplit(a), pb = packsplit(b);
      unsigned off = ((unsigned)(r*256 + 4*lane)) ^ (((unsigned)(r & 7)) << 4);
      *(unsigned*)((char*)&Xh[p][0] + off) = (pb & 0xFFFF0000u) | (pa >> 16);
      *(unsigned*)((char*)&Xl[p][0] + off) = (pb << 16) | (pa & 0xFFFFu);
      if (lane == 0) {
        float n = fmaxf(sqrtf(sq), 1e-8f);
        norms[p][r] = n;
        invs[p][r]  = 1.0f / n;
      }
    }
    #pragma unroll
    for (int rr = 0; rr < 8; ++rr) xpf[rr] = xn[rr];
    LGKM_BAR();                                       // bar1: X[p] ready

    // ---- Phase B: mm1 (X[p] x B1 regs), quantize, write Q[p] ----
    f32x16 accA, accB;
    #pragma unroll
    for (int g = 0; g < 16; ++g) { accA[g] = 0.0f; accB[g] = 0.0f; }
    __builtin_amdgcn_s_setprio(1);
    #pragma unroll
    for (int t = 0; t < 8; ++t) {
      unsigned fb = ((unsigned)(al*256 + t*32 + ah*16)) ^ (((unsigned)(al & 7)) << 4);
      short8 xh = *(const short8*)((const char*)&Xh[p][0] + fb);
      short8 xl = *(const short8*)((const char*)&Xl[p][0] + fb);
      if (t & 1) { MM3(accB, xh, xl, B1h[t], B1l[t]); }
      else       { MM3(accA, xh, xl, B1h[t], B1l[t]); }
    }
    __builtin_amdgcn_s_setprio(0);
    #pragma unroll
    for (int g = 0; g < 16; ++g) accA[g] += accB[g];

    unsigned qp[16];
    unsigned flags = 0;
    #pragma unroll
    for (int g = 0; g < 16; ++g) {
      const int r = (g & 3) + 8*(g >> 2) + 4*ah;
      float xr = accA[g] * invs[p][r];
      unsigned q = qt0;
      q = (xr > mid0) ? qt1 : q;  q = (xr > mid1) ? qt2 : q;
      q = (xr > mid2) ? qt3 : q;  q = (xr > mid3) ? qt4 : q;
      q = (xr > mid4) ? qt5 : q;  q = (xr > mid5) ? qt6 : q;
      q = (xr > mid6) ? qt7 : q;
      float dm = fabsf(xr - mid0);
      dm = fminf(dm, fabsf(xr - mid1)); dm = fminf(dm, fabsf(xr - mid2));
      dm = fminf(dm, fabsf(xr - mid3)); dm = fminf(dm, fabsf(xr - mid4));
      dm = fminf(dm, fabsf(xr - mid5)); dm = fminf(dm, fabsf(xr - mid6));
      qp[g] = q;
      flags |= (dm < MARGIN) ? (1u << g) : 0u;
    }
    #pragma unroll
    for (int g = 0; g < 16; ++g) {
      const int rq = (g & 3) + 8*(g >> 2) + 4*ah;
      unsigned off = ((unsigned)(rq*256 + (w*32 + al)*2)) ^ (((unsigned)(rq & 7)) << 4);
      *(unsigned short*)((char*)&Qh[p][0] + off) = (unsigned short)(qp[g] >> 16);
      *(unsigned short*)((char*)&Ql[p][0] + off) = (unsigned short)(qp[g] & 0xFFFFu);
    }
    if (__builtin_amdgcn_ballot_w64(flags != 0)) {   // rare path
      #pragma unroll
      for (int g = 0; g < 16; ++g) {
        unsigned long long b = __ballot((flags >> g) & 1u);
        if (b) {
          const int rq = (g & 3) + 8*(g >> 2) + 4*ah;
          unsigned base = 0;
          if (lane == 0) base = atomicAdd(counter, (unsigned)__popcll(b));
          base = (unsigned)__shfl((int)base, 0);
          if ((flags >> g) & 1u) {
            unsigned pp = base + (unsigned)__popcll(b & ((1ull << lane) - 1ull));
            if (pp < LIST_CAP) list[pp] = (unsigned)(chb + rq);
          }
        }
      }
    }
    LGKM_BAR();                                       // bar2: Q[p] ready

    // ---- Phase C: mm2 (Q[p] x B2 regs), scale + store ----
    f32x16 acc2, acc3;
    #pragma unroll
    for (int g = 0; g < 16; ++g) { acc2[g] = 0.0f; acc3[g] = 0.0f; }
    __builtin_amdgcn_s_setprio(1);
    #pragma unroll
    for (int t = 0; t < 8; ++t) {
      unsigned fb = ((unsigned)(al*256 + t*32 + ah*16)) ^ (((unsigned)(al & 7)) << 4);
      short8 xh = *(const short8*)((const char*)&Qh[p][0] + fb);
      short8 xl = *(const short8*)((const char*)&Ql[p][0] + fb);
      if (t & 1) { MM3(acc3, xh, xl, B2h[t], B2l[t]); }
      else       { MM3(acc2, xh, xl, B2h[t], B2l[t]); }
    }
    __builtin_amdgcn_s_setprio(0);

    #pragma unroll
    for (int g = 0; g < 16; ++g) {
      const int rq = (g & 3) + 8*(g >> 2) + 4*ah;
      float o = fmaf(acc2[g] + acc3[g], norms[p][rq], meanv);
      out[(size_t)(chb + rq)*128 + w*32 + al] = o;
    }
  }
}

// =======================================================================
// K_fix: exact f64 recompute of rows with any element within MARGIN of
// a quantization midpoint. One wave per row; overwrites out.
// =======================================================================
__global__ __launch_bounds__(256)
void kfix(const float* __restrict__ x, const float* __restrict__ mean,
          const float* __restrict__ cent, const double* __restrict__ Rt64,
          float* __restrict__ out,
          const unsigned int* __restrict__ counter,
          const unsigned int* __restrict__ list)
{
  __shared__ double xs[4][128];
  __shared__ double qs[4][128];
  const int tid = threadIdx.x, lane = tid & 63, w = tid >> 6;

  unsigned cnt = *counter;
  if (cnt > LIST_CAP) cnt = LIST_CAP;

  const double cc0 = (double)cent[0], cc1 = (double)cent[1], cc2 = (double)cent[2],
               cc3 = (double)cent[3], cc4 = (double)cent[4], cc5 = (double)cent[5],
               cc6 = (double)cent[6], cc7 = (double)cent[7];
  const double m0 = 0.5*(cc0+cc1), m1 = 0.5*(cc1+cc2), m2 = 0.5*(cc2+cc3),
               m3 = 0.5*(cc3+cc4), m4 = 0.5*(cc4+cc5), m5 = 0.5*(cc5+cc6),
               m6 = 0.5*(cc6+cc7);

  const unsigned gw = blockIdx.x*4 + w, stride = gridDim.x*4;
  for (unsigned e = gw; e < cnt; e += stride) {
    const int row = (int)list[e];
    const float* xr = x + (size_t)row*128;
    const int j0 = 2*lane;

    double a = (double)xr[j0]   - (double)mean[j0];
    double b = (double)xr[j0+1] - (double)mean[j0+1];
    double s = a*a + b*b;
    s += __shfl_xor(s, 1);  s += __shfl_xor(s, 2);  s += __shfl_xor(s, 4);
    s += __shfl_xor(s, 8);  s += __shfl_xor(s, 16); s += __shfl_xor(s, 32);
    double n = sqrt(s);
    if (n < 1e-8) n = 1e-8;
    double inv = 1.0 / n;
    xs[w][j0]   = a * inv;
    xs[w][j0+1] = b * inv;
    asm volatile("s_waitcnt lgkmcnt(0)" ::: "memory");

    double acc0 = 0.0, acc1 = 0.0;
    for (int j = 0; j < 128; ++j) {
      double xj = xs[w][j];
      acc0 = fma(xj, Rt64[j*128 + j0],     acc0);
      acc1 = fma(xj, Rt64[j*128 + j0 + 1], acc1);
    }
    double q0 = cc0;
    q0 = (acc0 > m0) ? cc1 : q0;  q0 = (acc0 > m1) ? cc2 : q0;
    q0 = (acc0 > m2) ? cc3 : q0;  q0 = (acc0 > m3) ? cc4 : q0;
    q0 = (acc0 > m4) ? cc5 : q0;  q0 = (acc0 > m5) ? cc6 : q0;
    q0 = (acc0 > m6) ? cc7 : q0;
    double q1 = cc0;
    q1 = (acc1 > m0) ? cc1 : q1;  q1 = (acc1 > m1) ? cc2 : q1;
    q1 = (acc1 > m2) ? cc3 : q1;  q1 = (acc1 > m3) ? cc4 : q1;
    q1 = (acc1 > m4) ? cc5 : q1;  q1 = (acc1 > m5) ? cc6 : q1;
    q1 = (acc1 > m6) ? cc7 : q1;
    qs[w][j0]   = q0;
    qs[w][j0+1] = q1;
    asm volatile("s_waitcnt lgkmcnt(0)" ::: "memory");

    double o0 = 0.0, o1 = 0.0;
    for (int k = 0; k < 128; ++k) {
      double qk = qs[w][k];
      o0 = fma(qk, Rt64[j0*128 + k],       o0);
      o1 = fma(qk, Rt64[(j0+1)*128 + k],   o1);
    }
    out[(size_t)row*128 + j0]   = (float)fma(o0, n, (double)mean[j0]);
    out[(size_t)row*128 + j0+1] = (float)fma(o1, n, (double)mean[j0+1]);
  }
}

// =======================================================================
extern "C" void kernel_launch(void* const* d_in, const int* in_sizes, int n_in,
                              void* d_out, int out_size, void* d_ws, size_t ws_size,
                              hipStream_t stream)
{
  (void)in_sizes; (void)n_in; (void)out_size; (void)ws_size;
  const float* x    = (const float*)d_in[0];
  const float* skew = (const float*)d_in[1];
  const float* cent = (const float*)d_in[2];
  const float* mean = (const float*)d_in[3];
  float* out = (float*)d_out;

  char* ws = (char*)d_ws;
  double*         Rt64 = (double*)(ws);
  unsigned short* img  = (unsigned short*)(ws + 131072);
  unsigned int*   cntr = (unsigned int*)(ws + 262144);
  unsigned int*   list = (unsigned int*)(ws + 262912);

  hipMemsetAsync(cntr, 0, 4, stream);
  kpre <<<dim3(1),    dim3(1024), 0, stream>>>(skew, Rt64, img);
  kmain<<<dim3(1024), dim3(256),  0, stream>>>(x, mean, cent, img, out, cntr, list);
  kfix <<<dim3(256),  dim3(256),  0, stream>>>(x, mean, cent, Rt64, out, cntr, list);
}

// Round 8
// 468.908 us; speedup vs baseline: 1.0103x; 1.0103x over previous
//
#include <hip/hip_runtime.h>

#define BATCH 262144
#define MARGIN 1e-5f
#define LIST_CAP (1u<<20)

typedef __attribute__((ext_vector_type(8))) short short8;
typedef __attribute__((ext_vector_type(16))) float f32x16;

// ---------------- workspace layout (bytes) ----------------
// 0       : Rt64 f64[128][128]  Rt64[j*128+k] = R[k][j]      (131072)
// 131072  : img  u16: i1h[16384] i1l[16384] i2h[16384] i2l[16384] (131072)
//           img1 frag(kb,jc): lane l,e -> R[kb*32+(l&31)][jc*16+8*(l>>5)+e]  (mm1 B)
//           img2 frag(jb,kc): lane l,e -> R[kc*16+8*(l>>5)+e][jb*32+(l&31)]  (mm2 B)
// 262144  : counter u32
// 262912  : list u32[LIST_CAP]  (row ids, dups ok)

__device__ __forceinline__ unsigned f2bf(float f) {
  unsigned u = __float_as_uint(f);
  return (u + 0x7FFFu + ((u >> 16) & 1u)) >> 16;   // RTN-even bf16
}
__device__ __forceinline__ unsigned packsplit(float f) {
  unsigned h = f2bf(f);
  float hf = __uint_as_float(h << 16);
  unsigned l = f2bf(f - hf);
  return (h << 16) | l;
}

// =======================================================================
// K_pre: Gauss-Jordan inversion of M = I + A (no pivoting; cond ~1.5).
// Per-thread row-slice held in 16 NAMED f64 SCALARS m0..m15 (an array
// was never SROA-promoted -> scratch -> 27 MB FETCH, 320 us). Runtime
// selects done via cndmask chains. One barrier per iteration.
// R = 2*(I+A)^-1 - I.
// =======================================================================
#define FOR_ALL_M(OP) \
  OP(0,m0) OP(1,m1) OP(2,m2) OP(3,m3) OP(4,m4) OP(5,m5) OP(6,m6) OP(7,m7) \
  OP(8,m8) OP(9,m9) OP(10,m10) OP(11,m11) OP(12,m12) OP(13,m13) OP(14,m14) OP(15,m15)

__global__ __launch_bounds__(1024, 4)
void kpre(const float* __restrict__ skew, double* __restrict__ Rt64,
          unsigned short* __restrict__ img)
{
  __shared__ double colk[2][128];   // raw pivot-column values per row
  __shared__ double praw[2][128];   // raw (unscaled) pivot row
  const int tid = threadIdx.x;
  const int i = tid >> 3;
  const int s = tid & 7;

  double m0,m1,m2,m3,m4,m5,m6,m7,m8,m9,m10,m11,m12,m13,m14,m15;

#define INIT(E,ME) { const int j = s + 8*(E);                              \
    if (i == j)      ME = 1.0;                                             \
    else if (i < j)  ME =  (double)skew[i*127 - (i*(i-1))/2 + (j-i-1)];    \
    else             ME = -(double)skew[j*127 - (j*(j-1))/2 + (i-j-1)]; }
  FOR_ALL_M(INIT)
#undef INIT

  // prologue: publish column 0 and raw row 0
  if (s == 0) colk[0][i] = m0;
  if (i == 0) {
#define PUB0(E,ME) praw[0][s + 8*(E)] = ME;
    FOR_ALL_M(PUB0)
#undef PUB0
  }
  __syncthreads();

  for (int k = 0; k < 128; ++k) {
    const int p = k & 1, np = p ^ 1;
    const int kp1 = k + 1;
    const int ns = kp1 & 7, ne = kp1 >> 3;   // k=127 -> ne=16: no publish
    const double rec = 1.0 / colk[p][k];     // redundant in all threads
    const bool piv = (i == k);
    const double t = piv ? 0.0 : colk[p][i] * rec;

#define STEP(E,ME) {                                                       \
    const int j = s + 8*(E);                                               \
    double vp = (j == k) ? rec : ME * rec;               /* pivot row  */  \
    double vn = (j == k) ? (0.0 - t)                                       \
                         : fma(-t, praw[p][j], ME);      /* eliminate  */  \
    ME = piv ? vp : vn; }
    FOR_ALL_M(STEP)
#undef STEP

    // publish next raw pivot row (static stores, one row of threads)
    if (i == kp1) {
#define PUBR(E,ME) praw[np][s + 8*(E)] = ME;
      FOR_ALL_M(PUBR)
#undef PUBR
    }
    // publish next raw pivot column: element (E == ne) via select chain
    if (s == ns && kp1 < 128) {
      double pub = m0;
#define SEL(E,ME) pub = (ne == (E)) ? ME : pub;
      FOR_ALL_M(SEL)
#undef SEL
      colk[np][i] = pub;
    }
    __syncthreads();
  }

#define EPI(E,ME) {                                                        \
    const int j = s + 8*(E);                                               \
    double v = 2.0 * ME - ((i == j) ? 1.0 : 0.0);   /* R[i][j] */          \
    Rt64[j*128 + i] = v;                                                   \
    float r32 = (float)v;                                                  \
    unsigned h = f2bf(r32);                                                \
    unsigned l = f2bf(r32 - __uint_as_float(h << 16));                     \
    int off1 = (((i>>5)*8 + (j>>4))*64 + ((((j>>3)&1)<<5) | (i&31)))*8 + (j&7); \
    img[off1]          = (unsigned short)h;                                \
    img[16384 + off1]  = (unsigned short)l;                                \
    int off2 = (((j>>5)*8 + (i>>4))*64 + ((((i>>3)&1)<<5) | (j&31)))*8 + (i&7); \
    img[32768 + off2]  = (unsigned short)h;                                \
    img[49152 + off2]  = (unsigned short)l; }
  FOR_ALL_M(EPI)
#undef EPI
}

// =======================================================================
// K_main: fused rotate+quantize+reconstruct. 1024 blocks x 256 thr.
// B-fragments in registers for the whole kernel. X/Q LDS double-buffered.
// Barriers are lgkm-only (no vmcnt drain): out-stores and next-chunk
// prefetch loads stay in flight across barriers.
// =======================================================================
#define MM3(ACC, XH, XL, BH, BL)                                        \
  ACC = __builtin_amdgcn_mfma_f32_32x32x16_bf16(XH, BH, ACC, 0, 0, 0);  \
  ACC = __builtin_amdgcn_mfma_f32_32x32x16_bf16(XL, BH, ACC, 0, 0, 0);  \
  ACC = __builtin_amdgcn_mfma_f32_32x32x16_bf16(XH, BL, ACC, 0, 0, 0);

#define LGKM_BAR()                                                      \
  asm volatile("s_waitcnt lgkmcnt(0)" ::: "memory");                    \
  __builtin_amdgcn_s_barrier();                                         \
  __builtin_amdgcn_sched_barrier(0);

__global__ __launch_bounds__(256, 2)
void kmain(const float* __restrict__ x, const float* __restrict__ mean,
           const float* __restrict__ cent, const unsigned short* __restrict__ img,
           float* __restrict__ out,
           unsigned int* __restrict__ counter, unsigned int* __restrict__ list)
{
  __shared__ __align__(16) unsigned short Xh[2][32*128];   // 2 x 8 KB (swizzled)
  __shared__ __align__(16) unsigned short Xl[2][32*128];
  __shared__ __align__(16) unsigned short Qh[2][32*128];
  __shared__ __align__(16) unsigned short Ql[2][32*128];
  __shared__ float norms[2][32];
  __shared__ float invs[2][32];

  const int tid = threadIdx.x, lane = tid & 63, w = tid >> 6;
  const int al = lane & 31, ah = lane >> 5;

  // ---- loop-invariant B fragments -> registers (128 VGPRs) ----
  short8 B1h[8], B1l[8], B2h[8], B2l[8];
  #pragma unroll
  for (int t = 0; t < 8; ++t) {
    size_t o = (size_t)((w*8 + t)*64 + lane)*8;
    B1h[t] = *(const short8*)(img +         o);
    B1l[t] = *(const short8*)(img + 16384 + o);
    B2h[t] = *(const short8*)(img + 32768 + o);
    B2l[t] = *(const short8*)(img + 49152 + o);
  }

  const float c0 = cent[0], c1 = cent[1], c2 = cent[2], c3 = cent[3];
  const float c4 = cent[4], c5 = cent[5], c6 = cent[6], c7 = cent[7];
  const float mid0 = 0.5f*(c0+c1), mid1 = 0.5f*(c1+c2), mid2 = 0.5f*(c2+c3),
              mid3 = 0.5f*(c3+c4), mid4 = 0.5f*(c4+c5), mid5 = 0.5f*(c5+c6),
              mid6 = 0.5f*(c6+c7);
  const unsigned qt0 = packsplit(c0), qt1 = packsplit(c1), qt2 = packsplit(c2),
                 qt3 = packsplit(c3), qt4 = packsplit(c4), qt5 = packsplit(c5),
                 qt6 = packsplit(c6), qt7 = packsplit(c7);

  const float2 mean2 = *(const float2*)(mean + 2*lane);
  const float meanv = mean[w*32 + al];

  const int row0 = blockIdx.x * 256;

  // prefetch chunk 0
  float2 xpf[8];
  #pragma unroll
  for (int rr = 0; rr < 8; ++rr)
    xpf[rr] = *(const float2*)(x + (size_t)(row0 + w*8 + rr)*128 + 2*lane);

  for (int ch = 0; ch < 8; ++ch) {
    const int chb = row0 + ch*32;
    const int p = ch & 1;

    // ---- Phase A: issue next-chunk loads; pack current -> X[p] ----
    float2 xn[8];
    if (ch < 7) {
      #pragma unroll
      for (int rr = 0; rr < 8; ++rr)
        xn[rr] = *(const float2*)(x + (size_t)(chb + 32 + w*8 + rr)*128 + 2*lane);
    }
    #pragma unroll
    for (int rr = 0; rr < 8; ++rr) {
      const int r = w*8 + rr;
      float a = xpf[rr].x - mean2.x;
      float b = xpf[rr].y - mean2.y;
      float sq = fmaf(a, a, b*b);
      sq += __shfl_xor(sq, 1);  sq += __shfl_xor(sq, 2);  sq += __shfl_xor(sq, 4);
      sq += __shfl_xor(sq, 8);  sq += __shfl_xor(sq, 16); sq += __shfl_xor(sq, 32);
      unsigned pa = packsplit(a), pb = packsplit(b);
      unsigned off = ((unsigned)(r*256 + 4*lane)) ^ (((unsigned)(r & 7)) << 4);
      *(unsigned*)((char*)&Xh[p][0] + off) = (pb & 0xFFFF0000u) | (pa >> 16);
      *(unsigned*)((char*)&Xl[p][0] + off) = (pb << 16) | (pa & 0xFFFFu);
      if (lane == 0) {
        float n = fmaxf(sqrtf(sq), 1e-8f);
        norms[p][r] = n;
        invs[p][r]  = 1.0f / n;
      }
    }
    #pragma unroll
    for (int rr = 0; rr < 8; ++rr) xpf[rr] = xn[rr];
    LGKM_BAR();                                       // bar1: X[p] ready

    // ---- Phase B: mm1 (X[p] x B1 regs), quantize, write Q[p] ----
    f32x16 accA, accB;
    #pragma unroll
    for (int g = 0; g < 16; ++g) { accA[g] = 0.0f; accB[g] = 0.0f; }
    __builtin_amdgcn_s_setprio(1);
    #pragma unroll
    for (int t = 0; t < 8; ++t) {
      unsigned fb = ((unsigned)(al*256 + t*32 + ah*16)) ^ (((unsigned)(al & 7)) << 4);
      short8 xh = *(const short8*)((const char*)&Xh[p][0] + fb);
      short8 xl = *(const short8*)((const char*)&Xl[p][0] + fb);
      if (t & 1) { MM3(accB, xh, xl, B1h[t], B1l[t]); }
      else       { MM3(accA, xh, xl, B1h[t], B1l[t]); }
    }
    __builtin_amdgcn_s_setprio(0);
    #pragma unroll
    for (int g = 0; g < 16; ++g) accA[g] += accB[g];

    unsigned qp[16];
    unsigned flags = 0;
    #pragma unroll
    for (int g = 0; g < 16; ++g) {
      const int r = (g & 3) + 8*(g >> 2) + 4*ah;
      float xr = accA[g] * invs[p][r];
      unsigned q = qt0;
      q = (xr > mid0) ? qt1 : q;  q = (xr > mid1) ? qt2 : q;
      q = (xr > mid2) ? qt3 : q;  q = (xr > mid3) ? qt4 : q;
      q = (xr > mid4) ? qt5 : q;  q = (xr > mid5) ? qt6 : q;
      q = (xr > mid6) ? qt7 : q;
      float dm = fabsf(xr - mid0);
      dm = fminf(dm, fabsf(xr - mid1)); dm = fminf(dm, fabsf(xr - mid2));
      dm = fminf(dm, fabsf(xr - mid3)); dm = fminf(dm, fabsf(xr - mid4));
      dm = fminf(dm, fabsf(xr - mid5)); dm = fminf(dm, fabsf(xr - mid6));
      qp[g] = q;
      flags |= (dm < MARGIN) ? (1u << g) : 0u;
    }
    #pragma unroll
    for (int g = 0; g < 16; ++g) {
      const int rq = (g & 3) + 8*(g >> 2) + 4*ah;
      unsigned off = ((unsigned)(rq*256 + (w*32 + al)*2)) ^ (((unsigned)(rq & 7)) << 4);
      *(unsigned short*)((char*)&Qh[p][0] + off) = (unsigned short)(qp[g] >> 16);
      *(unsigned short*)((char*)&Ql[p][0] + off) = (unsigned short)(qp[g] & 0xFFFFu);
    }
    if (__builtin_amdgcn_ballot_w64(flags != 0)) {   // rare path
      #pragma unroll
      for (int g = 0; g < 16; ++g) {
        unsigned long long b = __ballot((flags >> g) & 1u);
        if (b) {
          const int rq = (g & 3) + 8*(g >> 2) + 4*ah;
          unsigned base = 0;
          if (lane == 0) base = atomicAdd(counter, (unsigned)__popcll(b));
          base = (unsigned)__shfl((int)base, 0);
          if ((flags >> g) & 1u) {
            unsigned pp = base + (unsigned)__popcll(b & ((1ull << lane) - 1ull));
            if (pp < LIST_CAP) list[pp] = (unsigned)(chb + rq);
          }
        }
      }
    }
    LGKM_BAR();                                       // bar2: Q[p] ready

    // ---- Phase C: mm2 (Q[p] x B2 regs), scale + store ----
    f32x16 acc2, acc3;
    #pragma unroll
    for (int g = 0; g < 16; ++g) { acc2[g] = 0.0f; acc3[g] = 0.0f; }
    __builtin_amdgcn_s_setprio(1);
    #pragma unroll
    for (int t = 0; t < 8; ++t) {
      unsigned fb = ((unsigned)(al*256 + t*32 + ah*16)) ^ (((unsigned)(al & 7)) << 4);
      short8 xh = *(const short8*)((const char*)&Qh[p][0] + fb);
      short8 xl = *(const short8*)((const char*)&Ql[p][0] + fb);
      if (t & 1) { MM3(acc3, xh, xl, B2h[t], B2l[t]); }
      else       { MM3(acc2, xh, xl, B2h[t], B2l[t]); }
    }
    __builtin_amdgcn_s_setprio(0);

    #pragma unroll
    for (int g = 0; g < 16; ++g) {
      const int rq = (g & 3) + 8*(g >> 2) + 4*ah;
      float o = fmaf(acc2[g] + acc3[g], norms[p][rq], meanv);
      out[(size_t)(chb + rq)*128 + w*32 + al] = o;
    }
  }
}

// =======================================================================
// K_fix: exact f64 recompute of rows with any element within MARGIN of
// a quantization midpoint. One wave per row; overwrites out.
// =======================================================================
__global__ __launch_bounds__(256)
void kfix(const float* __restrict__ x, const float* __restrict__ mean,
          const float* __restrict__ cent, const double* __restrict__ Rt64,
          float* __restrict__ out,
          const unsigned int* __restrict__ counter,
          const unsigned int* __restrict__ list)
{
  __shared__ double xs[4][128];
  __shared__ double qs[4][128];
  const int tid = threadIdx.x, lane = tid & 63, w = tid >> 6;

  unsigned cnt = *counter;
  if (cnt > LIST_CAP) cnt = LIST_CAP;

  const double cc0 = (double)cent[0], cc1 = (double)cent[1], cc2 = (double)cent[2],
               cc3 = (double)cent[3], cc4 = (double)cent[4], cc5 = (double)cent[5],
               cc6 = (double)cent[6], cc7 = (double)cent[7];
  const double m0 = 0.5*(cc0+cc1), m1 = 0.5*(cc1+cc2), m2 = 0.5*(cc2+cc3),
               m3 = 0.5*(cc3+cc4), m4 = 0.5*(cc4+cc5), m5 = 0.5*(cc5+cc6),
               m6 = 0.5*(cc6+cc7);

  const unsigned gw = blockIdx.x*4 + w, stride = gridDim.x*4;
  for (unsigned e = gw; e < cnt; e += stride) {
    const int row = (int)list[e];
    const float* xr = x + (size_t)row*128;
    const int j0 = 2*lane;

    double a = (double)xr[j0]   - (double)mean[j0];
    double b = (double)xr[j0+1] - (double)mean[j0+1];
    double s = a*a + b*b;
    s += __shfl_xor(s, 1);  s += __shfl_xor(s, 2);  s += __shfl_xor(s, 4);
    s += __shfl_xor(s, 8);  s += __shfl_xor(s, 16); s += __shfl_xor(s, 32);
    double n = sqrt(s);
    if (n < 1e-8) n = 1e-8;
    double inv = 1.0 / n;
    xs[w][j0]   = a * inv;
    xs[w][j0+1] = b * inv;
    asm volatile("s_waitcnt lgkmcnt(0)" ::: "memory");

    double acc0 = 0.0, acc1 = 0.0;
    for (int j = 0; j < 128; ++j) {
      double xj = xs[w][j];
      acc0 = fma(xj, Rt64[j*128 + j0],     acc0);
      acc1 = fma(xj, Rt64[j*128 + j0 + 1], acc1);
    }
    double q0 = cc0;
    q0 = (acc0 > m0) ? cc1 : q0;  q0 = (acc0 > m1) ? cc2 : q0;
    q0 = (acc0 > m2) ? cc3 : q0;  q0 = (acc0 > m3) ? cc4 : q0;
    q0 = (acc0 > m4) ? cc5 : q0;  q0 = (acc0 > m5) ? cc6 : q0;
    q0 = (acc0 > m6) ? cc7 : q0;
    double q1 = cc0;
    q1 = (acc1 > m0) ? cc1 : q1;  q1 = (acc1 > m1) ? cc2 : q1;
    q1 = (acc1 > m2) ? cc3 : q1;  q1 = (acc1 > m3) ? cc4 : q1;
    q1 = (acc1 > m4) ? cc5 : q1;  q1 = (acc1 > m5) ? cc6 : q1;
    q1 = (acc1 > m6) ? cc7 : q1;
    qs[w][j0]   = q0;
    qs[w][j0+1] = q1;
    asm volatile("s_waitcnt lgkmcnt(0)" ::: "memory");

    double o0 = 0.0, o1 = 0.0;
    for (int k = 0; k < 128; ++k) {
      double qk = qs[w][k];
      o0 = fma(qk, Rt64[j0*128 + k],       o0);
      o1 = fma(qk, Rt64[(j0+1)*128 + k],   o1);
    }
    out[(size_t)row*128 + j0]   = (float)fma(o0, n, (double)mean[j0]);
    out[(size_t)row*128 + j0+1] = (float)fma(o1, n, (double)mean[j0+1]);
  }
}

// =======================================================================
extern "C" void kernel_launch(void* const* d_in, const int* in_sizes, int n_in,
                              void* d_out, int out_size, void* d_ws, size_t ws_size,
                              hipStream_t stream)
{
  (void)in_sizes; (void)n_in; (void)out_size; (void)ws_size;
  const float* x    = (const float*)d_in[0];
  const float* skew = (const float*)d_in[1];
  const float* cent = (const float*)d_in[2];
  const float* mean = (const float*)d_in[3];
  float* out = (float*)d_out;

  char* ws = (char*)d_ws;
  double*         Rt64 = (double*)(ws);
  unsigned short* img  = (unsigned short*)(ws + 131072);
  unsigned int*   cntr = (unsigned int*)(ws + 262144);
  unsigned int*   list = (unsigned int*)(ws + 262912);

  hipMemsetAsync(cntr, 0, 4, stream);
  kpre <<<dim3(1),    dim3(1024), 0, stream>>>(skew, Rt64, img);
  kmain<<<dim3(1024), dim3(256),  0, stream>>>(x, mean, cent, img, out, cntr, list);
  kfix <<<dim3(256),  dim3(256),  0, stream>>>(x, mean, cent, Rt64, out, cntr, list);
}

// Round 9
// 292.695 us; speedup vs baseline: 1.6186x; 1.6020x over previous
//
#include <hip/hip_runtime.h>

#define BATCH 262144
#define MARGIN 1e-5f
#define LIST_CAP (1u<<20)

typedef __attribute__((ext_vector_type(8))) short short8;
typedef __attribute__((ext_vector_type(16))) float f32x16;

// ---------------- workspace layout (bytes) ----------------
// 0       : Rt64 f64[128][128]  Rt64[j*128+k] = R[k][j]      (131072)
// 131072  : img  u16: i1h[16384] i1l[16384] i2h[16384] i2l[16384] (131072)
// 262144  : counter u32
// 262912  : list u32[LIST_CAP]                                (4 MB)
// 4457216 : M64 f64[128][128]   I+A (exact)                   (131072)
// 4588288 : Y64 f64[128][128]   f32-GJ inverse (promoted)     (131072)
// 4719360 : Yb  f64[128][128]   Newton intermediate           (131072)

__device__ __forceinline__ unsigned f2bf(float f) {
  unsigned u = __float_as_uint(f);
  return (u + 0x7FFFu + ((u >> 16) & 1u)) >> 16;   // RTN-even bf16
}
__device__ __forceinline__ unsigned packsplit(float f) {
  unsigned h = f2bf(f);
  float hf = __uint_as_float(h << 16);
  unsigned l = f2bf(f - hf);
  return (h << 16) | l;
}

// =======================================================================
// K_pre32: f32 Gauss-Jordan inversion of M = I + A (no pivoting; sym
// part of every Schur complement is I => pivots >= 1, stable). Exact
// round-5 structure (fastest measured) with f32 state (16 VGPR). Writes
// M64 = I+A (exact, at init) and Y64 = f32 inverse. Accuracy of Y64 is
// NON-critical: kref's two f64 Newton steps square the residual to
// ~1e-15 regardless.
// =======================================================================
__global__ __launch_bounds__(1024, 4)
void kpre32(const float* __restrict__ skew, double* __restrict__ M64,
            double* __restrict__ Y64)
{
  __shared__ float colk[2][128];
  __shared__ float pivrow[128];
  const int tid = threadIdx.x;
  const int i = tid >> 3;
  const int s = tid & 7;

  float M[16];
  #pragma unroll
  for (int e = 0; e < 16; ++e) {
    int j = s + 8*e;
    float v;
    if (i == j)      v = 1.0f;
    else if (i < j)  v =  skew[i*127 - (i*(i-1))/2 + (j - i - 1)];
    else             v = -skew[j*127 - (j*(j-1))/2 + (i - j - 1)];
    M[e] = v;
    M64[i*128 + j] = (double)v;     // exact I+A
  }
  if (s == 0) colk[0][i] = M[0];
  __syncthreads();

  for (int k = 0; k < 128; ++k) {
    const int p = k & 1, np = p ^ 1;
    const int ns = (k + 1) & 7, ne = (k + 1) >> 3;
    if (i == k) {
      float rec = 1.0f / colk[p][k];
      #pragma unroll
      for (int e = 0; e < 16; ++e) {
        int j = s + 8*e;
        float v = (j == k) ? 1.0f : M[e];
        v *= rec;
        M[e] = v;
        pivrow[j] = v;
      }
      if (s == ns && k < 127) colk[np][i] = M[ne];
    }
    __syncthreads();
    if (i != k) {
      float f = colk[p][i];
      #pragma unroll
      for (int e = 0; e < 16; ++e) {
        int j = s + 8*e;
        float v = (j == k) ? 0.0f : M[e];
        M[e] = fmaf(-f, pivrow[j], v);
      }
      if (s == ns && k < 127) colk[np][i] = M[ne];
    }
    __syncthreads();
  }

  #pragma unroll
  for (int e = 0; e < 16; ++e) {
    int j = s + 8*e;
    Y64[i*128 + j] = (double)M[e];
  }
}

// =======================================================================
// K_ref: one f64 Newton-Schulz step Yout = Yin*(2I - M64*Yin), computed
// per 16-column tile (8 blocks). final_pass: instead of Yout, emit
// R = 2*Y2 - I as Rt64 + bf16-split fragment images.
// =======================================================================
__global__ __launch_bounds__(256, 2)
void kref(const double* __restrict__ M64, const double* __restrict__ Yin,
          double* __restrict__ Yout, double* __restrict__ Rt64,
          unsigned short* __restrict__ img, const int final_pass)
{
  __shared__ double Yc[128][17];
  __shared__ double T[128][17];
  const int t = threadIdx.x;
  const int c0 = blockIdx.x * 16;

  // stage Yin[:, c0:c0+16]
  #pragma unroll
  for (int u = 0; u < 8; ++u) {
    int idx = u*256 + t;
    int row = idx >> 4, cc = idx & 15;
    Yc[row][cc] = Yin[row*128 + c0 + cc];
  }
  __syncthreads();

  const int m = t >> 1;            // 0..127 (row of T / output row)
  const int h = (t & 1) * 8;       // column half within tile

  // T[m][h..h+7] = sum_j M64[m][j] * Yc[j][h..h+7]
  double a0=0,a1=0,a2=0,a3=0,a4=0,a5=0,a6=0,a7=0;
  for (int j = 0; j < 128; ++j) {
    double mv = M64[m*128 + j];
    a0 = fma(mv, Yc[j][h+0], a0);  a1 = fma(mv, Yc[j][h+1], a1);
    a2 = fma(mv, Yc[j][h+2], a2);  a3 = fma(mv, Yc[j][h+3], a3);
    a4 = fma(mv, Yc[j][h+4], a4);  a5 = fma(mv, Yc[j][h+5], a5);
    a6 = fma(mv, Yc[j][h+6], a6);  a7 = fma(mv, Yc[j][h+7], a7);
  }
  T[m][h+0]=a0; T[m][h+1]=a1; T[m][h+2]=a2; T[m][h+3]=a3;
  T[m][h+4]=a4; T[m][h+5]=a5; T[m][h+6]=a6; T[m][h+7]=a7;
  __syncthreads();

  // B[m][h..h+7] = sum_j Yin[m][j] * T[j][h..h+7]
  double b0=0,b1=0,b2=0,b3=0,b4=0,b5=0,b6=0,b7=0;
  for (int j = 0; j < 128; ++j) {
    double yv = Yin[m*128 + j];
    b0 = fma(yv, T[j][h+0], b0);  b1 = fma(yv, T[j][h+1], b1);
    b2 = fma(yv, T[j][h+2], b2);  b3 = fma(yv, T[j][h+3], b3);
    b4 = fma(yv, T[j][h+4], b4);  b5 = fma(yv, T[j][h+5], b5);
    b6 = fma(yv, T[j][h+6], b6);  b7 = fma(yv, T[j][h+7], b7);
  }

  double y2[8] = { 2.0*Yc[m][h+0]-b0, 2.0*Yc[m][h+1]-b1, 2.0*Yc[m][h+2]-b2,
                   2.0*Yc[m][h+3]-b3, 2.0*Yc[m][h+4]-b4, 2.0*Yc[m][h+5]-b5,
                   2.0*Yc[m][h+6]-b6, 2.0*Yc[m][h+7]-b7 };

  if (!final_pass) {
    #pragma unroll
    for (int c = 0; c < 8; ++c) Yout[m*128 + c0 + h + c] = y2[c];
  } else {
    #pragma unroll
    for (int c = 0; c < 8; ++c) {
      const int i = m, j = c0 + h + c;
      double v = 2.0*y2[c] - ((i == j) ? 1.0 : 0.0);    // R[i][j]
      Rt64[j*128 + i] = v;
      float r32 = (float)v;
      unsigned hh = f2bf(r32);
      unsigned ll = f2bf(r32 - __uint_as_float(hh << 16));
      int off1 = (((i>>5)*8 + (j>>4))*64 + ((((j>>3)&1)<<5) | (i&31)))*8 + (j&7);
      img[off1]          = (unsigned short)hh;
      img[16384 + off1]  = (unsigned short)ll;
      int off2 = (((j>>5)*8 + (i>>4))*64 + ((((i>>3)&1)<<5) | (j&31)))*8 + (i&7);
      img[32768 + off2]  = (unsigned short)hh;
      img[49152 + off2]  = (unsigned short)ll;
    }
  }
}

// =======================================================================
// K_main: fused rotate+quantize+reconstruct. 1024 blocks x 256 thr.
// B-fragments in registers for the whole kernel. X/Q LDS double-buffered.
// Barriers are lgkm-only (no vmcnt drain).
// =======================================================================
#define MM3(ACC, XH, XL, BH, BL)                                        \
  ACC = __builtin_amdgcn_mfma_f32_32x32x16_bf16(XH, BH, ACC, 0, 0, 0);  \
  ACC = __builtin_amdgcn_mfma_f32_32x32x16_bf16(XL, BH, ACC, 0, 0, 0);  \
  ACC = __builtin_amdgcn_mfma_f32_32x32x16_bf16(XH, BL, ACC, 0, 0, 0);

#define LGKM_BAR()                                                      \
  asm volatile("s_waitcnt lgkmcnt(0)" ::: "memory");                    \
  __builtin_amdgcn_s_barrier();                                         \
  __builtin_amdgcn_sched_barrier(0);

__global__ __launch_bounds__(256, 2)
void kmain(const float* __restrict__ x, const float* __restrict__ mean,
           const float* __restrict__ cent, const unsigned short* __restrict__ img,
           float* __restrict__ out,
           unsigned int* __restrict__ counter, unsigned int* __restrict__ list)
{
  __shared__ __align__(16) unsigned short Xh[2][32*128];
  __shared__ __align__(16) unsigned short Xl[2][32*128];
  __shared__ __align__(16) unsigned short Qh[2][32*128];
  __shared__ __align__(16) unsigned short Ql[2][32*128];
  __shared__ float norms[2][32];
  __shared__ float invs[2][32];

  const int tid = threadIdx.x, lane = tid & 63, w = tid >> 6;
  const int al = lane & 31, ah = lane >> 5;

  short8 B1h[8], B1l[8], B2h[8], B2l[8];
  #pragma unroll
  for (int t = 0; t < 8; ++t) {
    size_t o = (size_t)((w*8 + t)*64 + lane)*8;
    B1h[t] = *(const short8*)(img +         o);
    B1l[t] = *(const short8*)(img + 16384 + o);
    B2h[t] = *(const short8*)(img + 32768 + o);
    B2l[t] = *(const short8*)(img + 49152 + o);
  }

  const float c0 = cent[0], c1 = cent[1], c2 = cent[2], c3 = cent[3];
  const float c4 = cent[4], c5 = cent[5], c6 = cent[6], c7 = cent[7];
  const float mid0 = 0.5f*(c0+c1), mid1 = 0.5f*(c1+c2), mid2 = 0.5f*(c2+c3),
              mid3 = 0.5f*(c3+c4), mid4 = 0.5f*(c4+c5), mid5 = 0.5f*(c5+c6),
              mid6 = 0.5f*(c6+c7);
  const unsigned qt0 = packsplit(c0), qt1 = packsplit(c1), qt2 = packsplit(c2),
                 qt3 = packsplit(c3), qt4 = packsplit(c4), qt5 = packsplit(c5),
                 qt6 = packsplit(c6), qt7 = packsplit(c7);

  const float2 mean2 = *(const float2*)(mean + 2*lane);
  const float meanv = mean[w*32 + al];

  const int row0 = blockIdx.x * 256;

  float2 xpf[8];
  #pragma unroll
  for (int rr = 0; rr < 8; ++rr)
    xpf[rr] = *(const float2*)(x + (size_t)(row0 + w*8 + rr)*128 + 2*lane);

  for (int ch = 0; ch < 8; ++ch) {
    const int chb = row0 + ch*32;
    const int p = ch & 1;

    float2 xn[8];
    if (ch < 7) {
      #pragma unroll
      for (int rr = 0; rr < 8; ++rr)
        xn[rr] = *(const float2*)(x + (size_t)(chb + 32 + w*8 + rr)*128 + 2*lane);
    }
    #pragma unroll
    for (int rr = 0; rr < 8; ++rr) {
      const int r = w*8 + rr;
      float a = xpf[rr].x - mean2.x;
      float b = xpf[rr].y - mean2.y;
      float sq = fmaf(a, a, b*b);
      sq += __shfl_xor(sq, 1);  sq += __shfl_xor(sq, 2);  sq += __shfl_xor(sq, 4);
      sq += __shfl_xor(sq, 8);  sq += __shfl_xor(sq, 16); sq += __shfl_xor(sq, 32);
      unsigned pa = packsplit(a), pb = packsplit(b);
      unsigned off = ((unsigned)(r*256 + 4*lane)) ^ (((unsigned)(r & 7)) << 4);
      *(unsigned*)((char*)&Xh[p][0] + off) = (pb & 0xFFFF0000u) | (pa >> 16);
      *(unsigned*)((char*)&Xl[p][0] + off) = (pb << 16) | (pa & 0xFFFFu);
      if (lane == 0) {
        float n = fmaxf(sqrtf(sq), 1e-8f);
        norms[p][r] = n;
        invs[p][r]  = 1.0f / n;
      }
    }
    #pragma unroll
    for (int rr = 0; rr < 8; ++rr) xpf[rr] = xn[rr];
    LGKM_BAR();                                       // bar1: X[p] ready

    f32x16 accA, accB;
    #pragma unroll
    for (int g = 0; g < 16; ++g) { accA[g] = 0.0f; accB[g] = 0.0f; }
    __builtin_amdgcn_s_setprio(1);
    #pragma unroll
    for (int t = 0; t < 8; ++t) {
      unsigned fb = ((unsigned)(al*256 + t*32 + ah*16)) ^ (((unsigned)(al & 7)) << 4);
      short8 xh = *(const short8*)((const char*)&Xh[p][0] + fb);
      short8 xl = *(const short8*)((const char*)&Xl[p][0] + fb);
      if (t & 1) { MM3(accB, xh, xl, B1h[t], B1l[t]); }
      else       { MM3(accA, xh, xl, B1h[t], B1l[t]); }
    }
    __builtin_amdgcn_s_setprio(0);
    #pragma unroll
    for (int g = 0; g < 16; ++g) accA[g] += accB[g];

    unsigned qp[16];
    unsigned flags = 0;
    #pragma unroll
    for (int g = 0; g < 16; ++g) {
      const int r = (g & 3) + 8*(g >> 2) + 4*ah;
      float xr = accA[g] * invs[p][r];
      unsigned q = qt0;
      q = (xr > mid0) ? qt1 : q;  q = (xr > mid1) ? qt2 : q;
      q = (xr > mid2) ? qt3 : q;  q = (xr > mid3) ? qt4 : q;
      q = (xr > mid4) ? qt5 : q;  q = (xr > mid5) ? qt6 : q;
      q = (xr > mid6) ? qt7 : q;
      float dm = fabsf(xr - mid0);
      dm = fminf(dm, fabsf(xr - mid1)); dm = fminf(dm, fabsf(xr - mid2));
      dm = fminf(dm, fabsf(xr - mid3)); dm = fminf(dm, fabsf(xr - mid4));
      dm = fminf(dm, fabsf(xr - mid5)); dm = fminf(dm, fabsf(xr - mid6));
      qp[g] = q;
      flags |= (dm < MARGIN) ? (1u << g) : 0u;
    }
    #pragma unroll
    for (int g = 0; g < 16; ++g) {
      const int rq = (g & 3) + 8*(g >> 2) + 4*ah;
      unsigned off = ((unsigned)(rq*256 + (w*32 + al)*2)) ^ (((unsigned)(rq & 7)) << 4);
      *(unsigned short*)((char*)&Qh[p][0] + off) = (unsigned short)(qp[g] >> 16);
      *(unsigned short*)((char*)&Ql[p][0] + off) = (unsigned short)(qp[g] & 0xFFFFu);
    }
    if (__builtin_amdgcn_ballot_w64(flags != 0)) {   // rare path
      #pragma unroll
      for (int g = 0; g < 16; ++g) {
        unsigned long long b = __ballot((flags >> g) & 1u);
        if (b) {
          const int rq = (g & 3) + 8*(g >> 2) + 4*ah;
          unsigned base = 0;
          if (lane == 0) base = atomicAdd(counter, (unsigned)__popcll(b));
          base = (unsigned)__shfl((int)base, 0);
          if ((flags >> g) & 1u) {
            unsigned pp = base + (unsigned)__popcll(b & ((1ull << lane) - 1ull));
            if (pp < LIST_CAP) list[pp] = (unsigned)(chb + rq);
          }
        }
      }
    }
    LGKM_BAR();                                       // bar2: Q[p] ready

    f32x16 acc2, acc3;
    #pragma unroll
    for (int g = 0; g < 16; ++g) { acc2[g] = 0.0f; acc3[g] = 0.0f; }
    __builtin_amdgcn_s_setprio(1);
    #pragma unroll
    for (int t = 0; t < 8; ++t) {
      unsigned fb = ((unsigned)(al*256 + t*32 + ah*16)) ^ (((unsigned)(al & 7)) << 4);
      short8 xh = *(const short8*)((const char*)&Qh[p][0] + fb);
      short8 xl = *(const short8*)((const char*)&Ql[p][0] + fb);
      if (t & 1) { MM3(acc3, xh, xl, B2h[t], B2l[t]); }
      else       { MM3(acc2, xh, xl, B2h[t], B2l[t]); }
    }
    __builtin_amdgcn_s_setprio(0);

    #pragma unroll
    for (int g = 0; g < 16; ++g) {
      const int rq = (g & 3) + 8*(g >> 2) + 4*ah;
      float o = fmaf(acc2[g] + acc3[g], norms[p][rq], meanv);
      out[(size_t)(chb + rq)*128 + w*32 + al] = o;
    }
  }
}

// =======================================================================
// K_fix: exact f64 recompute of rows with any element within MARGIN of
// a quantization midpoint. One wave per row; overwrites out.
// =======================================================================
__global__ __launch_bounds__(256)
void kfix(const float* __restrict__ x, const float* __restrict__ mean,
          const float* __restrict__ cent, const double* __restrict__ Rt64,
          float* __restrict__ out,
          const unsigned int* __restrict__ counter,
          const unsigned int* __restrict__ list)
{
  __shared__ double xs[4][128];
  __shared__ double qs[4][128];
  const int tid = threadIdx.x, lane = tid & 63, w = tid >> 6;

  unsigned cnt = *counter;
  if (cnt > LIST_CAP) cnt = LIST_CAP;

  const double cc0 = (double)cent[0], cc1 = (double)cent[1], cc2 = (double)cent[2],
               cc3 = (double)cent[3], cc4 = (double)cent[4], cc5 = (double)cent[5],
               cc6 = (double)cent[6], cc7 = (double)cent[7];
  const double m0 = 0.5*(cc0+cc1), m1 = 0.5*(cc1+cc2), m2 = 0.5*(cc2+cc3),
               m3 = 0.5*(cc3+cc4), m4 = 0.5*(cc4+cc5), m5 = 0.5*(cc5+cc6),
               m6 = 0.5*(cc6+cc7);

  const unsigned gw = blockIdx.x*4 + w, stride = gridDim.x*4;
  for (unsigned e = gw; e < cnt; e += stride) {
    const int row = (int)list[e];
    const float* xr = x + (size_t)row*128;
    const int j0 = 2*lane;

    double a = (double)xr[j0]   - (double)mean[j0];
    double b = (double)xr[j0+1] - (double)mean[j0+1];
    double s = a*a + b*b;
    s += __shfl_xor(s, 1);  s += __shfl_xor(s, 2);  s += __shfl_xor(s, 4);
    s += __shfl_xor(s, 8);  s += __shfl_xor(s, 16); s += __shfl_xor(s, 32);
    double n = sqrt(s);
    if (n < 1e-8) n = 1e-8;
    double inv = 1.0 / n;
    xs[w][j0]   = a * inv;
    xs[w][j0+1] = b * inv;
    asm volatile("s_waitcnt lgkmcnt(0)" ::: "memory");

    double acc0 = 0.0, acc1 = 0.0;
    for (int j = 0; j < 128; ++j) {
      double xj = xs[w][j];
      acc0 = fma(xj, Rt64[j*128 + j0],     acc0);
      acc1 = fma(xj, Rt64[j*128 + j0 + 1], acc1);
    }
    double q0 = cc0;
    q0 = (acc0 > m0) ? cc1 : q0;  q0 = (acc0 > m1) ? cc2 : q0;
    q0 = (acc0 > m2) ? cc3 : q0;  q0 = (acc0 > m3) ? cc4 : q0;
    q0 = (acc0 > m4) ? cc5 : q0;  q0 = (acc0 > m5) ? cc6 : q0;
    q0 = (acc0 > m6) ? cc7 : q0;
    double q1 = cc0;
    q1 = (acc1 > m0) ? cc1 : q1;  q1 = (acc1 > m1) ? cc2 : q1;
    q1 = (acc1 > m2) ? cc3 : q1;  q1 = (acc1 > m3) ? cc4 : q1;
    q1 = (acc1 > m4) ? cc5 : q1;  q1 = (acc1 > m5) ? cc6 : q1;
    q1 = (acc1 > m6) ? cc7 : q1;
    qs[w][j0]   = q0;
    qs[w][j0+1] = q1;
    asm volatile("s_waitcnt lgkmcnt(0)" ::: "memory");

    double o0 = 0.0, o1 = 0.0;
    for (int k = 0; k < 128; ++k) {
      double qk = qs[w][k];
      o0 = fma(qk, Rt64[j0*128 + k],       o0);
      o1 = fma(qk, Rt64[(j0+1)*128 + k],   o1);
    }
    out[(size_t)row*128 + j0]   = (float)fma(o0, n, (double)mean[j0]);
    out[(size_t)row*128 + j0+1] = (float)fma(o1, n, (double)mean[j0+1]);
  }
}

// =======================================================================
extern "C" void kernel_launch(void* const* d_in, const int* in_sizes, int n_in,
                              void* d_out, int out_size, void* d_ws, size_t ws_size,
                              hipStream_t stream)
{
  (void)in_sizes; (void)n_in; (void)out_size; (void)ws_size;
  const float* x    = (const float*)d_in[0];
  const float* skew = (const float*)d_in[1];
  const float* cent = (const float*)d_in[2];
  const float* mean = (const float*)d_in[3];
  float* out = (float*)d_out;

  char* ws = (char*)d_ws;
  double*         Rt64 = (double*)(ws);
  unsigned short* img  = (unsigned short*)(ws + 131072);
  unsigned int*   cntr = (unsigned int*)(ws + 262144);
  unsigned int*   list = (unsigned int*)(ws + 262912);
  double*         M64  = (double*)(ws + 4457216);
  double*         Y64  = (double*)(ws + 4588288);
  double*         Yb   = (double*)(ws + 4719360);

  hipMemsetAsync(cntr, 0, 4, stream);
  kpre32<<<dim3(1),    dim3(1024), 0, stream>>>(skew, M64, Y64);
  kref  <<<dim3(8),    dim3(256),  0, stream>>>(M64, Y64, Yb, Rt64, img, 0);
  kref  <<<dim3(8),    dim3(256),  0, stream>>>(M64, Yb, Y64, Rt64, img, 1);
  kmain <<<dim3(1024), dim3(256),  0, stream>>>(x, mean, cent, img, out, cntr, list);
  kfix  <<<dim3(256),  dim3(256),  0, stream>>>(x, mean, cent, Rt64, out, cntr, list);
}